// Round 16
// baseline (188.137 us; speedup 1.0000x reference)
//
#include <hip/hip_runtime.h>
#include <hip/hip_bf16.h>
#include <cstdint>
#include <cstddef>

#define NROWS 8192
#define KDIM  2048
#define ODIM  1000
#define NSUB  8
#define OPAD  1024   // padded output dim for Wt

#define BM 256
#define BN 256
#define BK 32
#define KSPLIT 2
#define KHALF (KDIM / KSPLIT)    // 1024 -> 32 K-tiles per block
#define NT 4                     // OPAD / BN
#define MT_MAX 5                 // 5 x 256 = 1280 rows/subject covered
#define ASLOT (BM * BK)          // 8192 elems (16KB)
#define SLOT  ((BM + BN) * BK)   // 16384 elems (32KB)

typedef __attribute__((ext_vector_type(4))) float f32x4;
typedef __attribute__((ext_vector_type(8))) short short8v;
typedef __attribute__((ext_vector_type(4))) unsigned short u16x4;
typedef __attribute__((ext_vector_type(4))) int int4v;

__device__ __forceinline__ unsigned short f2bf(float f){
  unsigned u = __builtin_bit_cast(unsigned, f);
  unsigned r = (u + 0x7FFFu + ((u >> 16) & 1u)) >> 16;  // RNE
  return (unsigned short)r;
}

__device__ __forceinline__ void gload16(const void* g, void* l){
  __builtin_amdgcn_global_load_lds(
      (const __attribute__((address_space(1))) void*)g,
      (__attribute__((address_space(3))) void*)l, 16, 0, 0);
}

// ---------------- K1: build perm/counts/offsets in ONE kernel ----------------
__global__ __launch_bounds__(256) void build_perm(const int* __restrict__ sid,
                                                  int* __restrict__ counts,
                                                  int* __restrict__ offsets,
                                                  int* __restrict__ perm){
  int s = blockIdx.x;
  __shared__ int shs[NROWS];          // 32KB cached sid
  __shared__ int red_lt[4], red_eq[4], wsum[4];
  __shared__ int sh_base;

  int t = threadIdx.x, lane = t & 63, wv = t >> 6;

  int c_lt = 0, c_eq = 0;
  const int4v* sv = (const int4v*)sid;
  #pragma unroll
  for (int i = 0; i < NROWS / 4 / 256; i++){
    int idx = i * 256 + t;
    int4v v = sv[idx];
    *(int4v*)&shs[idx * 4] = v;
    #pragma unroll
    for (int e = 0; e < 4; e++){ c_lt += (v[e] < s); c_eq += (v[e] == s); }
  }
  #pragma unroll
  for (int d = 32; d >= 1; d >>= 1){
    c_lt += __shfl_xor(c_lt, d);
    c_eq += __shfl_xor(c_eq, d);
  }
  if (lane == 0){ red_lt[wv] = c_lt; red_eq[wv] = c_eq; }
  __syncthreads();
  if (t == 0){
    int lt = red_lt[0] + red_lt[1] + red_lt[2] + red_lt[3];
    int eq = red_eq[0] + red_eq[1] + red_eq[2] + red_eq[3];
    offsets[s] = lt;
    counts[s]  = eq;
    sh_base = lt;
  }
  __syncthreads();
  int base = sh_base;

  for (int c0 = 0; c0 < NROWS; c0 += 256){
    int v = shs[c0 + t];
    bool eq = (v == s);
    unsigned long long m = __ballot(eq);
    int rk = __popcll(m & ((1ull << lane) - 1ull));
    int wc = __popcll(m);
    if (lane == 0) wsum[wv] = wc;
    __syncthreads();
    int woff = 0;
    #pragma unroll
    for (int w = 0; w < 4; w++) if (w < wv) woff += wsum[w];
    int tot = wsum[0] + wsum[1] + wsum[2] + wsum[3];
    if (eq) perm[base + woff + rk] = c0 + t;
    base += tot;
    __syncthreads();
  }
}

// ---------------- K2a: streaming cvt x fp32 -> xb bf16 (no gather) ----------------
__global__ __launch_bounds__(256) void cvt_x(const float* __restrict__ x,
                                             unsigned short* __restrict__ xb){
  int b = blockIdx.x;
  int t = threadIdx.x;
  size_t base = (size_t)b * 8192 + (size_t)t * 8;
  #pragma unroll
  for (int c = 0; c < 4; c++){
    size_t f = base + (size_t)c * 2048;
    f32x4 v0 = *(const f32x4*)(x + f);
    f32x4 v1 = *(const f32x4*)(x + f + 4);
    short8v o;
    o[0] = (short)f2bf(v0[0]); o[1] = (short)f2bf(v0[1]);
    o[2] = (short)f2bf(v0[2]); o[3] = (short)f2bf(v0[3]);
    o[4] = (short)f2bf(v1[0]); o[5] = (short)f2bf(v1[1]);
    o[6] = (short)f2bf(v1[2]); o[7] = (short)f2bf(v1[3]);
    *(short8v*)(xb + f) = o;
  }
}

// ---------------- K2b: transpose + cvt W[s][k][o] -> Wt[s][o][k] bf16 ----------------
__global__ __launch_bounds__(256) void transpose_w(const float* __restrict__ W,
                                                   unsigned short* __restrict__ Wt){
  __shared__ float tile[64][65];
  int b = blockIdx.x;
  int t = threadIdx.x;
  int s  = b >> 9;                    // 0..7
  int kt = (b >> 4) & 31;             // 0..31
  int ot = b & 15;                    // 0..15
  int k0 = kt * 64, o0 = ot * 64;

  int kr  = t >> 4;                   // load rows
  int ol4 = (t & 15) * 4;             // load cols (float4)
  bool lval = (o0 + ol4) < ODIM;

  const float* src = W + ((size_t)s * KDIM + k0) * ODIM + o0;
  #pragma unroll
  for (int it = 0; it < 4; it++){
    int k = kr + it * 16;
    f32x4 v = lval ? *(const f32x4*)(src + (size_t)k * ODIM + ol4)
                   : f32x4{0.f, 0.f, 0.f, 0.f};
    tile[k][ol4 + 0] = v[0]; tile[k][ol4 + 1] = v[1];
    tile[k][ol4 + 2] = v[2]; tile[k][ol4 + 3] = v[3];
  }
  __syncthreads();

  int j8   = (t & 7) * 8;
  int orow = t >> 3;
  unsigned short* dst = Wt + ((size_t)(s * OPAD + o0)) * KDIM + k0;
  #pragma unroll
  for (int it = 0; it < 2; it++){
    int o = orow + it * 32;
    bool oval = (o0 + o) < ODIM;
    short8v w;
    #pragma unroll
    for (int j = 0; j < 8; j++)
      w[j] = oval ? (short)f2bf(tile[j8 + j][o]) : (short)0;
    *(short8v*)(dst + (size_t)o * KDIM + j8) = w;
  }
}

// ---------------- K3: grouped bf16 MFMA GEMM, 256x256, split-K x2 ----------------
// m201 geometry: 8 waves (2Mx4N), wave-tile 128x64, acc[8][4], BK=32,
// 3-slot LDS ring (96KB). Per K-tile 2 phases; B-fragments REUSED in
// registers across M-half phases. Counted vmcnt(4) never drains mid-loop.
// Split-K x2 -> 256 active blocks (perfect packing). atomicAdd epilogue.
__global__ __launch_bounds__(512, 1) void gemm_bf16(
    const unsigned short* __restrict__ xb,   // [8192][2048] bf16 (orig order)
    const unsigned short* __restrict__ Wt,   // [8][1024][2048] bf16
    const int* __restrict__ counts,
    const int* __restrict__ offsets,
    const int* __restrict__ perm,
    const float* __restrict__ bias,          // [8][1000]
    float* __restrict__ out)                 // [8192][1000] (zeroed)
{
  int b  = blockIdx.x;
  int s  = b & 7;                 // subject == XCD
  int r  = b >> 3;
  int nt = r & 3;
  int r2 = r >> 2;
  int mt = r2 % MT_MAX;
  int kh = r2 / MT_MAX;           // 0 or 1
  int cnt = counts[s];
  int loc0 = mt * BM;
  if (loc0 >= cnt) return;
  int row0 = offsets[s] + loc0;
  int cnt_loc = cnt - loc0;
  size_t kbase = (size_t)kh * KHALF;

  __shared__ unsigned short L[3 * SLOT];     // 96KB ring
  __shared__ int permL[BM];                  // 1KB

  int t = threadIdx.x;
  int lane = t & 63;
  int wave = t >> 6;              // 0..7

  int wm = (wave >> 2) << 7;      // 0 or 128
  int wn = (wave & 3) << 6;       // 0,64,128,192
  int frow = lane & 15, fk = lane >> 4;
  int axor2 = (frow >> 1) & 3;    // read-side swizzle (2-way banks = free)

  // staging: 1KB round = 16 rows x 64B; lane l -> row l>>2, phys slot l&3.
  // source pre-swizzled: logical k-slot = (l&3) ^ ((l>>3)&3)  [= (row>>1)&3]
  int srck = (((lane & 3) ^ ((lane >> 3) & 3)) << 3);

  // prologue: per-lane perm'd A rows + permL (all drained before staging)
  int prow[2];
  #pragma unroll
  for (int rr = 0; rr < 2; rr++){
    int row = rr * 128 + wave * 16 + (lane >> 2);
    int pidx = row0 + row; if (pidx > NROWS - 1) pidx = NROWS - 1;
    prow[rr] = perm[pidx];
  }
  {
    int pr = t & 255;
    int pidx = row0 + pr; if (pidx > NROWS - 1) pidx = NROWS - 1;
    int pl = perm[pidx];
    asm volatile("s_waitcnt vmcnt(0)" ::: "memory");
    __builtin_amdgcn_sched_barrier(0);
    permL[pr] = pl;
  }

  size_t gA[2], gB[2]; unsigned loA[2], loB[2];
  #pragma unroll
  for (int rr = 0; rr < 2; rr++){
    int row = rr * 128 + wave * 16 + (lane >> 2);
    gA[rr] = (size_t)prow[rr] * KDIM + kbase + srck;
    gB[rr] = ((size_t)(s * OPAD + nt * BN + row)) * KDIM + kbase + srck;
    loA[rr] = (unsigned)(row * BK + (lane & 3) * 8);
    loB[rr] = (unsigned)(ASLOT + row * BK + (lane & 3) * 8);
  }

  f32x4 acc[8][4];
  #pragma unroll
  for (int i = 0; i < 8; i++)
    #pragma unroll
    for (int j = 0; j < 4; j++)
      #pragma unroll
      for (int e = 0; e < 4; e++) acc[i][j][e] = 0.f;

#define STAGE_A(sl, koff) do { \
    unsigned short* Ls = &L[(sl) * SLOT]; \
    gload16(xb + gA[0] + (koff), (void*)(Ls + loA[0])); \
    gload16(xb + gA[1] + (koff), (void*)(Ls + loA[1])); \
  } while (0)
#define STAGE_B(sl, koff) do { \
    unsigned short* Ls = &L[(sl) * SLOT]; \
    gload16(Wt + gB[0] + (koff), (void*)(Ls + loB[0])); \
    gload16(Wt + gB[1] + (koff), (void*)(Ls + loB[1])); \
  } while (0)

#define VMN() do { \
    asm volatile("s_waitcnt vmcnt(4)" ::: "memory"); \
    __builtin_amdgcn_sched_barrier(0); \
  } while (0)
#define VM0() do { \
    asm volatile("s_waitcnt vmcnt(0)" ::: "memory"); \
    __builtin_amdgcn_sched_barrier(0); \
  } while (0)

#define AOFF(mi) (((wm + ((mi) << 4) + frow) * BK) + ((fk ^ axor2) << 3))
#define BOFF(ni) (ASLOT + ((wn + ((ni) << 4) + frow) * BK) + ((fk ^ axor2) << 3))
#define MF(mi, ni, av, bv) acc[mi][ni] = __builtin_amdgcn_mfma_f32_16x16x32_bf16(av, bv, acc[mi][ni], 0, 0, 0)

// one K-tile: ph0 {a0-3,b0-3 reads + stageA | bar | lgkm | 16 MFMA | bar}
//             ph1 {a4-7 reads (b reused) + stageB | bar | lgkm | 16 MFMA | ENDW | bar}
#define TILE(sl, SA, SB, ENDW) do { \
    const unsigned short* Lb = &L[(sl) * SLOT]; \
    short8v a0 = *(const short8v*)&Lb[AOFF(0)]; \
    short8v a1 = *(const short8v*)&Lb[AOFF(1)]; \
    short8v a2 = *(const short8v*)&Lb[AOFF(2)]; \
    short8v a3 = *(const short8v*)&Lb[AOFF(3)]; \
    short8v b0 = *(const short8v*)&Lb[BOFF(0)]; \
    short8v b1 = *(const short8v*)&Lb[BOFF(1)]; \
    short8v b2 = *(const short8v*)&Lb[BOFF(2)]; \
    short8v b3 = *(const short8v*)&Lb[BOFF(3)]; \
    SA; \
    __builtin_amdgcn_s_barrier(); \
    asm volatile("s_waitcnt lgkmcnt(0)" ::: "memory"); \
    __builtin_amdgcn_sched_barrier(0); \
    __builtin_amdgcn_s_setprio(1); \
    MF(0, 0, a0, b0); MF(1, 0, a1, b0); MF(2, 0, a2, b0); MF(3, 0, a3, b0); \
    MF(0, 1, a0, b1); MF(1, 1, a1, b1); MF(2, 1, a2, b1); MF(3, 1, a3, b1); \
    MF(0, 2, a0, b2); MF(1, 2, a1, b2); MF(2, 2, a2, b2); MF(3, 2, a3, b2); \
    MF(0, 3, a0, b3); MF(1, 3, a1, b3); MF(2, 3, a2, b3); MF(3, 3, a3, b3); \
    __builtin_amdgcn_s_setprio(0); \
    __builtin_amdgcn_s_barrier(); \
    short8v a4 = *(const short8v*)&Lb[AOFF(4)]; \
    short8v a5 = *(const short8v*)&Lb[AOFF(5)]; \
    short8v a6 = *(const short8v*)&Lb[AOFF(6)]; \
    short8v a7 = *(const short8v*)&Lb[AOFF(7)]; \
    SB; \
    __builtin_amdgcn_s_barrier(); \
    asm volatile("s_waitcnt lgkmcnt(0)" ::: "memory"); \
    __builtin_amdgcn_sched_barrier(0); \
    __builtin_amdgcn_s_setprio(1); \
    MF(4, 0, a4, b0); MF(5, 0, a5, b0); MF(6, 0, a6, b0); MF(7, 0, a7, b0); \
    MF(4, 1, a4, b1); MF(5, 1, a5, b1); MF(6, 1, a6, b1); MF(7, 1, a7, b1); \
    MF(4, 2, a4, b2); MF(5, 2, a5, b2); MF(6, 2, a6, b2); MF(7, 2, a7, b2); \
    MF(4, 3, a4, b3); MF(5, 3, a5, b3); MF(6, 3, a6, b3); MF(7, 3, a7, b3); \
    __builtin_amdgcn_s_setprio(0); \
    ENDW; \
    __builtin_amdgcn_s_barrier(); \
  } while (0)

  // prologue: tiles 0,1 staged (slots 0,1); wait tile 0 only
  STAGE_A(0, 0); STAGE_B(0, 0);
  STAGE_A(1, BK); STAGE_B(1, BK);
  VMN();
  __builtin_amdgcn_s_barrier();

  // main loop: tiles 0..29 of 32 (10 iters x 3 slots); stage t+2 mid-tile
  for (int i = 0; i < 10; ++i){
    int kb = i * 3 * BK;
    TILE(0, STAGE_A(2, kb + 2 * BK), STAGE_B(2, kb + 2 * BK), VMN());
    TILE(1, STAGE_A(0, kb + 3 * BK), STAGE_B(0, kb + 3 * BK), VMN());
    TILE(2, STAGE_A(1, kb + 4 * BK), STAGE_B(1, kb + 4 * BK), VMN());
  }
  // tail: tiles 30 (slot 0), 31 (slot 1)
  TILE(0, , , VM0());
  TILE(1, , , );

  // epilogue: C/D layout col=lane&15, row=(lane>>4)*4+reg; split-K atomics
  float bvn[4]; int ocol[4];
  #pragma unroll
  for (int ni = 0; ni < 4; ni++){
    int o = nt * BN + wn + (ni << 4) + frow;
    ocol[ni] = o;
    bvn[ni] = (kh == 0 && o < ODIM) ? bias[s * ODIM + o] : 0.f;
  }
  #pragma unroll
  for (int mi = 0; mi < 8; mi++){
    int rbase = wm + (mi << 4) + (fk << 2);
    #pragma unroll
    for (int jj = 0; jj < 4; jj++){
      int rr = rbase + jj;
      if (rr < cnt_loc){
        int orow = permL[rr];
        #pragma unroll
        for (int ni = 0; ni < 4; ni++){
          if (ocol[ni] < ODIM)
            atomicAdd(&out[(size_t)orow * ODIM + ocol[ni]], acc[mi][ni][jj] + bvn[ni]);
        }
      }
    }
  }
#undef STAGE_A
#undef STAGE_B
#undef VMN
#undef VM0
#undef AOFF
#undef BOFF
#undef MF
#undef TILE
}

// ---------------- fallback: naive fp32 (only if ws too small) ----------------
__global__ __launch_bounds__(256) void naive_kernel(const float* __restrict__ x,
                                                    const int* __restrict__ sid,
                                                    const float* __restrict__ W,
                                                    const float* __restrict__ bias,
                                                    float* __restrict__ out){
  __shared__ float xr[KDIM];
  int row = blockIdx.x;
  int s = sid[row];
  for (int i = threadIdx.x; i < KDIM; i += 256) xr[i] = x[(size_t)row * KDIM + i];
  __syncthreads();
  int o = blockIdx.y * 256 + threadIdx.x;
  if (o >= ODIM) return;
  const float* w = W + (size_t)s * KDIM * ODIM + o;
  float acc = bias[s * ODIM + o];
  for (int k = 0; k < KDIM; k++) acc = fmaf(xr[k], w[(size_t)k * ODIM], acc);
  out[(size_t)row * ODIM + o] = acc;
}

extern "C" void kernel_launch(void* const* d_in, const int* in_sizes, int n_in,
                              void* d_out, int out_size, void* d_ws, size_t ws_size,
                              hipStream_t stream) {
  const float* x    = (const float*)d_in[0];
  const int*   sid  = (const int*)d_in[1];
  const float* W    = (const float*)d_in[2];
  const float* bias = (const float*)d_in[3];
  float* out = (float*)d_out;

  const size_t XB_BYTES = (size_t)NROWS * KDIM * 2;
  const size_t WT_BYTES = (size_t)NSUB * OPAD * KDIM * 2;
  const size_t need = 64 + (size_t)NROWS * 4 + XB_BYTES + WT_BYTES;

  if (ws_size < need){
    naive_kernel<<<dim3(NROWS, 4), 256, 0, stream>>>(x, sid, W, bias, out);
    return;
  }

  char* w = (char*)d_ws;
  int* counts  = (int*)w;                      // 8 ints
  int* offsets = counts + 8;                   // 8 ints
  int* perm    = (int*)(w + 64);               // 8192 ints
  unsigned short* xb = (unsigned short*)(w + 64 + (size_t)NROWS * 4);
  unsigned short* Wt = xb + (size_t)NROWS * KDIM;

  // zero-init out for split-K atomic accumulation (stream-ordered)
  hipMemsetAsync(out, 0, (size_t)NROWS * ODIM * sizeof(float), stream);

  build_perm  <<<NSUB, 256, 0, stream>>>(sid, counts, offsets, perm);
  cvt_x       <<<2048, 256, 0, stream>>>(x, xb);
  transpose_w <<<4096, 256, 0, stream>>>(W, Wt);
  gemm_bf16   <<<NSUB * NT * MT_MAX * KSPLIT, 512, 0, stream>>>(xb, Wt, counts, offsets, perm, bias, out);
}

// Round 17
// 125.931 us; speedup vs baseline: 1.4940x; 1.4940x over previous
//
#include <hip/hip_runtime.h>
#include <hip/hip_bf16.h>
#include <cstdint>
#include <cstddef>

#define NROWS 8192
#define KDIM  2048
#define ODIM  1000
#define NSUB  8
#define OPAD  1024   // padded output dim for Wt

#define BM 256
#define BN 256
#define BK 64
#define MT_MAX 5                 // 5 x 256 = 1280 rows/subject covered
#define NT 4                     // OPAD / BN
#define ASLOT (BM * BK)          // 16384 elems (32KB)
#define SLOT  ((BM + BN) * BK)   // 32768 elems (64KB)

typedef __attribute__((ext_vector_type(4))) float f32x4;
typedef __attribute__((ext_vector_type(8))) short short8v;
typedef __attribute__((ext_vector_type(4))) unsigned short u16x4;
typedef __attribute__((ext_vector_type(4))) int int4v;

__device__ __forceinline__ unsigned short f2bf(float f){
  unsigned u = __builtin_bit_cast(unsigned, f);
  unsigned r = (u + 0x7FFFu + ((u >> 16) & 1u)) >> 16;  // RNE
  return (unsigned short)r;
}

__device__ __forceinline__ void gload16(const void* g, void* l){
  __builtin_amdgcn_global_load_lds(
      (const __attribute__((address_space(1))) void*)g,
      (__attribute__((address_space(3))) void*)l, 16, 0, 0);
}

// ---------------- K1: fused build_perm (blocks 0-7) + streaming cvt (blocks 8+) ----------------
__global__ __launch_bounds__(256) void perm_cvt(const int* __restrict__ sid,
                                                int* __restrict__ counts,
                                                int* __restrict__ offsets,
                                                int* __restrict__ perm,
                                                const float* __restrict__ x,
                                                unsigned short* __restrict__ xb){
  int b = blockIdx.x;
  int t = threadIdx.x;

  if (b >= 8){
    // streaming cast: 8192 floats per block, fully coalesced
    size_t base = (size_t)(b - 8) * 8192 + (size_t)t * 8;
    #pragma unroll
    for (int c = 0; c < 4; c++){
      size_t f = base + (size_t)c * 2048;
      f32x4 v0 = *(const f32x4*)(x + f);
      f32x4 v1 = *(const f32x4*)(x + f + 4);
      short8v o;
      o[0] = (short)f2bf(v0[0]); o[1] = (short)f2bf(v0[1]);
      o[2] = (short)f2bf(v0[2]); o[3] = (short)f2bf(v0[3]);
      o[4] = (short)f2bf(v1[0]); o[5] = (short)f2bf(v1[1]);
      o[6] = (short)f2bf(v1[2]); o[7] = (short)f2bf(v1[3]);
      *(short8v*)(xb + f) = o;
    }
    return;
  }

  // build_perm for subject s = b (stable compaction)
  int s = b;
  __shared__ int shs[NROWS];          // 32KB cached sid
  __shared__ int red_lt[4], red_eq[4], wsum[4];
  __shared__ int sh_base;

  int lane = t & 63, wv = t >> 6;
  int c_lt = 0, c_eq = 0;
  const int4v* sv = (const int4v*)sid;
  #pragma unroll
  for (int i = 0; i < NROWS / 4 / 256; i++){
    int idx = i * 256 + t;
    int4v v = sv[idx];
    *(int4v*)&shs[idx * 4] = v;
    #pragma unroll
    for (int e = 0; e < 4; e++){ c_lt += (v[e] < s); c_eq += (v[e] == s); }
  }
  #pragma unroll
  for (int d = 32; d >= 1; d >>= 1){
    c_lt += __shfl_xor(c_lt, d);
    c_eq += __shfl_xor(c_eq, d);
  }
  if (lane == 0){ red_lt[wv] = c_lt; red_eq[wv] = c_eq; }
  __syncthreads();
  if (t == 0){
    int lt = red_lt[0] + red_lt[1] + red_lt[2] + red_lt[3];
    int eq = red_eq[0] + red_eq[1] + red_eq[2] + red_eq[3];
    offsets[s] = lt;
    counts[s]  = eq;
    sh_base = lt;
  }
  __syncthreads();
  int base = sh_base;

  for (int c0 = 0; c0 < NROWS; c0 += 256){
    int v = shs[c0 + t];
    bool eq = (v == s);
    unsigned long long m = __ballot(eq);
    int rk = __popcll(m & ((1ull << lane) - 1ull));
    int wc = __popcll(m);
    if (lane == 0) wsum[wv] = wc;
    __syncthreads();
    int woff = 0;
    #pragma unroll
    for (int w = 0; w < 4; w++) if (w < wv) woff += wsum[w];
    int tot = wsum[0] + wsum[1] + wsum[2] + wsum[3];
    if (eq) perm[base + woff + rk] = c0 + t;
    base += tot;
    __syncthreads();
  }
}

// ---------------- K2: transpose + cvt W[s][k][o] -> Wt[s][o][k] bf16 ----------------
__global__ __launch_bounds__(256) void transpose_w(const float* __restrict__ W,
                                                   unsigned short* __restrict__ Wt){
  __shared__ float tile[64][65];
  int b = blockIdx.x;
  int t = threadIdx.x;
  int s  = b >> 9;                    // 0..7
  int kt = (b >> 4) & 31;             // 0..31
  int ot = b & 15;                    // 0..15
  int k0 = kt * 64, o0 = ot * 64;

  int kr  = t >> 4;
  int ol4 = (t & 15) * 4;
  bool lval = (o0 + ol4) < ODIM;

  const float* src = W + ((size_t)s * KDIM + k0) * ODIM + o0;
  #pragma unroll
  for (int it = 0; it < 4; it++){
    int k = kr + it * 16;
    f32x4 v = lval ? *(const f32x4*)(src + (size_t)k * ODIM + ol4)
                   : f32x4{0.f, 0.f, 0.f, 0.f};
    tile[k][ol4 + 0] = v[0]; tile[k][ol4 + 1] = v[1];
    tile[k][ol4 + 2] = v[2]; tile[k][ol4 + 3] = v[3];
  }
  __syncthreads();

  int j8   = (t & 7) * 8;
  int orow = t >> 3;
  unsigned short* dst = Wt + ((size_t)(s * OPAD + o0)) * KDIM + k0;
  #pragma unroll
  for (int it = 0; it < 2; it++){
    int o = orow + it * 32;
    bool oval = (o0 + o) < ODIM;
    short8v w;
    #pragma unroll
    for (int j = 0; j < 8; j++)
      w[j] = oval ? (short)f2bf(tile[j8 + j][o]) : (short)0;
    *(short8v*)(dst + (size_t)o * KDIM + j8) = w;
  }
}

// ---------------- K3: grouped bf16 MFMA GEMM, 256x256, m201-faithful ----------------
// BK=64, 8 waves, wave-tile 128x64 (acc[8][4] in AGPRs), 2-slot dbuf 128KB,
// 4 quadrant-phases per K-tile with register reuse (a-halves x b-halves),
// next tile's 8 gloads issued at P1/P2, ONE vmcnt(0)+barrier per tile.
// XOR-swizzled staging (R4-verified conflict-free), subject->XCD mapping.
__global__ __launch_bounds__(512, 1) void gemm_bf16(
    const unsigned short* __restrict__ xb,   // [8192][2048] bf16 (orig order)
    const unsigned short* __restrict__ Wt,   // [8][1024][2048] bf16
    const int* __restrict__ counts,
    const int* __restrict__ offsets,
    const int* __restrict__ perm,
    const float* __restrict__ bias,          // [8][1000]
    float* __restrict__ out)                 // [8192][1000]
{
  int b  = blockIdx.x;
  int s  = b & 7;                 // subject == XCD
  int r  = b >> 3;
  int nt = r & 3;                 // 0..3
  int mt = r >> 2;                // 0..4
  int cnt = counts[s];
  int loc0 = mt * BM;
  if (loc0 >= cnt) return;
  int row0 = offsets[s] + loc0;
  int cnt_loc = cnt - loc0;

  __shared__ unsigned short L[2 * SLOT];     // 2 x 64KB dbuf
  __shared__ int permL[BM];                  // 1KB

  int t = threadIdx.x;
  int lane = t & 63;
  int wave = t >> 6;              // 0..7

  int wm = (wave >> 2) << 7;      // 0 or 128
  int wn = (wave & 3) << 6;       // 0,64,128,192
  int frow = lane & 15, fk = lane >> 4;
  int axor = frow & 7;

  // staging: per-thread 4 A-loads + 4 B-loads per tile. Load k covers
  // chunk idx = k*512 + t: row = idx>>3, phys 16B-slot j = idx&7 holding
  // logical slot j^(row&7) (pre-swizzled global source, linear LDS dest).
  int prow[4];
  #pragma unroll
  for (int k = 0; k < 4; k++){
    int idx = k * 512 + t;
    int row = idx >> 3;
    int pidx = row0 + row; if (pidx > NROWS - 1) pidx = NROWS - 1;
    prow[k] = perm[pidx];
  }
  {
    int pr = t & 255;
    int pidx = row0 + pr; if (pidx > NROWS - 1) pidx = NROWS - 1;
    int pl = perm[pidx];
    asm volatile("s_waitcnt vmcnt(0)" ::: "memory");   // drain prologue loads
    __builtin_amdgcn_sched_barrier(0);
    permL[pr] = pl;
  }

  size_t gA[4], gB[4]; unsigned loA[4], loB[4];
  #pragma unroll
  for (int k = 0; k < 4; k++){
    int idx = k * 512 + t;
    int row = idx >> 3;
    int jlog = (idx & 7) ^ (row & 7);
    gA[k]  = (size_t)prow[k] * KDIM + jlog * 8;
    gB[k]  = ((size_t)(s * OPAD + nt * BN + row)) * KDIM + jlog * 8;
    loA[k] = (unsigned)(idx * 8);
    loB[k] = (unsigned)(ASLOT + idx * 8);
  }

  f32x4 acc[8][4];
  #pragma unroll
  for (int i = 0; i < 8; i++)
    #pragma unroll
    for (int j = 0; j < 4; j++)
      #pragma unroll
      for (int e = 0; e < 4; e++) acc[i][j][e] = 0.f;

#define STAGE_A(sl, koff) do { \
    unsigned short* Ls = &L[(sl) * SLOT]; \
    gload16(xb + gA[0] + (koff), (void*)(Ls + loA[0])); \
    gload16(xb + gA[1] + (koff), (void*)(Ls + loA[1])); \
    gload16(xb + gA[2] + (koff), (void*)(Ls + loA[2])); \
    gload16(xb + gA[3] + (koff), (void*)(Ls + loA[3])); \
  } while (0)
#define STAGE_B(sl, koff) do { \
    unsigned short* Ls = &L[(sl) * SLOT]; \
    gload16(Wt + gB[0] + (koff), (void*)(Ls + loB[0])); \
    gload16(Wt + gB[1] + (koff), (void*)(Ls + loB[1])); \
    gload16(Wt + gB[2] + (koff), (void*)(Ls + loB[2])); \
    gload16(Wt + gB[3] + (koff), (void*)(Ls + loB[3])); \
  } while (0)

#define VM0() do { \
    asm volatile("s_waitcnt vmcnt(0)" ::: "memory"); \
    __builtin_amdgcn_sched_barrier(0); \
  } while (0)

#define AOFF(mi, ks) ((((wm + ((mi) << 4) + frow)) << 6) + (((((ks) << 2) + fk) ^ axor) << 3))
#define BOFF(ni, ks) (ASLOT + (((wn + ((ni) << 4) + frow)) << 6) + (((((ks) << 2) + fk) ^ axor) << 3))
#define MF(mi, ni, av, bv) acc[mi][ni] = __builtin_amdgcn_mfma_f32_16x16x32_bf16(av, bv, acc[mi][ni], 0, 0, 0)

#define BAR_LGKM() do { \
    __builtin_amdgcn_s_barrier(); \
    asm volatile("s_waitcnt lgkmcnt(0)" ::: "memory"); \
    __builtin_amdgcn_sched_barrier(0); \
  } while (0)

// one K-tile: 4 quadrant-phases with a/b register reuse.
#define TILE(sl, SA, SB, ENDW) do { \
    const unsigned short* Lb = &L[(sl) * SLOT]; \
    /* P1: a0-3 (2ks) + b0-1 (2ks) reads; stage-A next; 16 MFMA */ \
    short8v a00 = *(const short8v*)&Lb[AOFF(0, 0)]; \
    short8v a10 = *(const short8v*)&Lb[AOFF(1, 0)]; \
    short8v a20 = *(const short8v*)&Lb[AOFF(2, 0)]; \
    short8v a30 = *(const short8v*)&Lb[AOFF(3, 0)]; \
    short8v a01 = *(const short8v*)&Lb[AOFF(0, 1)]; \
    short8v a11 = *(const short8v*)&Lb[AOFF(1, 1)]; \
    short8v a21 = *(const short8v*)&Lb[AOFF(2, 1)]; \
    short8v a31 = *(const short8v*)&Lb[AOFF(3, 1)]; \
    short8v b00 = *(const short8v*)&Lb[BOFF(0, 0)]; \
    short8v b10 = *(const short8v*)&Lb[BOFF(1, 0)]; \
    short8v b01 = *(const short8v*)&Lb[BOFF(0, 1)]; \
    short8v b11 = *(const short8v*)&Lb[BOFF(1, 1)]; \
    SA; \
    BAR_LGKM(); \
    __builtin_amdgcn_s_setprio(1); \
    MF(0, 0, a00, b00); MF(1, 0, a10, b00); MF(2, 0, a20, b00); MF(3, 0, a30, b00); \
    MF(0, 1, a00, b10); MF(1, 1, a10, b10); MF(2, 1, a20, b10); MF(3, 1, a30, b10); \
    MF(0, 0, a01, b01); MF(1, 0, a11, b01); MF(2, 0, a21, b01); MF(3, 0, a31, b01); \
    MF(0, 1, a01, b11); MF(1, 1, a11, b11); MF(2, 1, a21, b11); MF(3, 1, a31, b11); \
    __builtin_amdgcn_s_setprio(0); \
    /* P2: b2-3 (2ks) reads; stage-B next; 16 MFMA (a0-3 reused) */ \
    short8v b20 = *(const short8v*)&Lb[BOFF(2, 0)]; \
    short8v b30 = *(const short8v*)&Lb[BOFF(3, 0)]; \
    short8v b21 = *(const short8v*)&Lb[BOFF(2, 1)]; \
    short8v b31 = *(const short8v*)&Lb[BOFF(3, 1)]; \
    SB; \
    BAR_LGKM(); \
    __builtin_amdgcn_s_setprio(1); \
    MF(0, 2, a00, b20); MF(1, 2, a10, b20); MF(2, 2, a20, b20); MF(3, 2, a30, b20); \
    MF(0, 3, a00, b30); MF(1, 3, a10, b30); MF(2, 3, a20, b30); MF(3, 3, a30, b30); \
    MF(0, 2, a01, b21); MF(1, 2, a11, b21); MF(2, 2, a21, b21); MF(3, 2, a31, b21); \
    MF(0, 3, a01, b31); MF(1, 3, a11, b31); MF(2, 3, a21, b31); MF(3, 3, a31, b31); \
    __builtin_amdgcn_s_setprio(0); \
    /* P3: a4-7 (2ks) reads; 16 MFMA (b0-1 reused) */ \
    short8v a40 = *(const short8v*)&Lb[AOFF(4, 0)]; \
    short8v a50 = *(const short8v*)&Lb[AOFF(5, 0)]; \
    short8v a60 = *(const short8v*)&Lb[AOFF(6, 0)]; \
    short8v a70 = *(const short8v*)&Lb[AOFF(7, 0)]; \
    short8v a41 = *(const short8v*)&Lb[AOFF(4, 1)]; \
    short8v a51 = *(const short8v*)&Lb[AOFF(5, 1)]; \
    short8v a61 = *(const short8v*)&Lb[AOFF(6, 1)]; \
    short8v a71 = *(const short8v*)&Lb[AOFF(7, 1)]; \
    BAR_LGKM(); \
    __builtin_amdgcn_s_setprio(1); \
    MF(4, 0, a40, b00); MF(5, 0, a50, b00); MF(6, 0, a60, b00); MF(7, 0, a70, b00); \
    MF(4, 1, a40, b10); MF(5, 1, a50, b10); MF(6, 1, a60, b10); MF(7, 1, a70, b10); \
    MF(4, 0, a41, b01); MF(5, 0, a51, b01); MF(6, 0, a61, b01); MF(7, 0, a71, b01); \
    MF(4, 1, a41, b11); MF(5, 1, a51, b11); MF(6, 1, a61, b11); MF(7, 1, a71, b11); \
    /* P4: 16 MFMA (all regs reused); end-of-tile wait + barrier */ \
    MF(4, 2, a40, b20); MF(5, 2, a50, b20); MF(6, 2, a60, b20); MF(7, 2, a70, b20); \
    MF(4, 3, a40, b30); MF(5, 3, a50, b30); MF(6, 3, a60, b30); MF(7, 3, a70, b30); \
    MF(4, 2, a41, b21); MF(5, 2, a51, b21); MF(6, 2, a61, b21); MF(7, 2, a71, b21); \
    MF(4, 3, a41, b31); MF(5, 3, a51, b31); MF(6, 3, a61, b31); MF(7, 3, a71, b31); \
    __builtin_amdgcn_s_setprio(0); \
    ENDW; \
    __builtin_amdgcn_s_barrier(); \
  } while (0)

  // prologue: stage tile 0 into slot 0, drain, barrier
  STAGE_A(0, 0);
  STAGE_B(0, 0);
  VM0();
  __builtin_amdgcn_s_barrier();

  // main loop: 32 K-tiles, 2-slot dbuf; tile T stages T+1 into slot (T+1)&1
  for (int i = 0; i < 15; ++i){
    int kb = i * 2 * BK;
    TILE(0, STAGE_A(1, kb + BK),     STAGE_B(1, kb + BK),     VM0());  // tile 2i
    TILE(1, STAGE_A(0, kb + 2 * BK), STAGE_B(0, kb + 2 * BK), VM0());  // tile 2i+1
  }
  TILE(0, STAGE_A(1, 31 * BK), STAGE_B(1, 31 * BK), VM0());            // tile 30
  TILE(1, , , );                                                       // tile 31

  // epilogue: C/D layout col=lane&15, row=(lane>>4)*4+reg
  float bvn[4]; int ocol[4];
  #pragma unroll
  for (int ni = 0; ni < 4; ni++){
    int o = nt * BN + wn + (ni << 4) + frow;
    ocol[ni] = o;
    bvn[ni] = (o < ODIM) ? bias[s * ODIM + o] : 0.f;
  }
  #pragma unroll
  for (int mi = 0; mi < 8; mi++){
    int rbase = wm + (mi << 4) + (fk << 2);
    #pragma unroll
    for (int jj = 0; jj < 4; jj++){
      int rr = rbase + jj;
      if (rr < cnt_loc){
        int orow = permL[rr];
        #pragma unroll
        for (int ni = 0; ni < 4; ni++){
          if (ocol[ni] < ODIM)
            out[(size_t)orow * ODIM + ocol[ni]] = acc[mi][ni][jj] + bvn[ni];
        }
      }
    }
  }
#undef STAGE_A
#undef STAGE_B
#undef VM0
#undef AOFF
#undef BOFF
#undef MF
#undef BAR_LGKM
#undef TILE
}

// ---------------- fallback: naive fp32 (only if ws too small) ----------------
__global__ __launch_bounds__(256) void naive_kernel(const float* __restrict__ x,
                                                    const int* __restrict__ sid,
                                                    const float* __restrict__ W,
                                                    const float* __restrict__ bias,
                                                    float* __restrict__ out){
  __shared__ float xr[KDIM];
  int row = blockIdx.x;
  int s = sid[row];
  for (int i = threadIdx.x; i < KDIM; i += 256) xr[i] = x[(size_t)row * KDIM + i];
  __syncthreads();
  int o = blockIdx.y * 256 + threadIdx.x;
  if (o >= ODIM) return;
  const float* w = W + (size_t)s * KDIM * ODIM + o;
  float acc = bias[s * ODIM + o];
  for (int k = 0; k < KDIM; k++) acc = fmaf(xr[k], w[(size_t)k * ODIM], acc);
  out[(size_t)row * ODIM + o] = acc;
}

extern "C" void kernel_launch(void* const* d_in, const int* in_sizes, int n_in,
                              void* d_out, int out_size, void* d_ws, size_t ws_size,
                              hipStream_t stream) {
  const float* x    = (const float*)d_in[0];
  const int*   sid  = (const int*)d_in[1];
  const float* W    = (const float*)d_in[2];
  const float* bias = (const float*)d_in[3];
  float* out = (float*)d_out;

  const size_t XB_BYTES = (size_t)NROWS * KDIM * 2;
  const size_t WT_BYTES = (size_t)NSUB * OPAD * KDIM * 2;
  const size_t need = 64 + (size_t)NROWS * 4 + XB_BYTES + WT_BYTES;

  if (ws_size < need){
    naive_kernel<<<dim3(NROWS, 4), 256, 0, stream>>>(x, sid, W, bias, out);
    return;
  }

  char* w = (char*)d_ws;
  int* counts  = (int*)w;                      // 8 ints
  int* offsets = counts + 8;                   // 8 ints
  int* perm    = (int*)(w + 64);               // 8192 ints
  unsigned short* xb = (unsigned short*)(w + 64 + (size_t)NROWS * 4);
  unsigned short* Wt = xb + (size_t)NROWS * KDIM;

  perm_cvt    <<<8 + 2048, 256, 0, stream>>>(sid, counts, offsets, perm, x, xb);
  transpose_w <<<4096, 256, 0, stream>>>(W, Wt);
  gemm_bf16   <<<NSUB * NT * MT_MAX, 512, 0, stream>>>(xb, Wt, counts, offsets, perm, bias, out);
}

// Round 18
// 87.391 us; speedup vs baseline: 2.1528x; 1.4410x over previous
//
#include <hip/hip_runtime.h>
#include <hip/hip_bf16.h>
#include <cstdint>
#include <cstddef>

#define NROWS 8192
#define KDIM  2048
#define ODIM  1000
#define NSUB  8
#define OPAD  1024   // padded output dim for Wt

#define BM 160
#define BN 256
#define BK 64
#define MT_MAX 8                 // 8 x 160 = 1280 rows/subject covered
#define ASLOT (BM * BK)          // 10240 elems (20KB)
#define SLOT  ((BM + BN) * BK)   // 26624 elems (53248B)

typedef __attribute__((ext_vector_type(4))) float f32x4;
typedef __attribute__((ext_vector_type(8))) short short8v;
typedef __attribute__((ext_vector_type(4))) unsigned short u16x4;
typedef __attribute__((ext_vector_type(4))) int int4v;

__device__ __forceinline__ unsigned short f2bf(float f){
  unsigned u = __builtin_bit_cast(unsigned, f);
  unsigned r = (u + 0x7FFFu + ((u >> 16) & 1u)) >> 16;  // RNE
  return (unsigned short)r;
}

__device__ __forceinline__ void gload16(const void* g, void* l){
  __builtin_amdgcn_global_load_lds(
      (const __attribute__((address_space(1))) void*)g,
      (__attribute__((address_space(3))) void*)l, 16, 0, 0);
}

// ---------------- K1: fused build_perm (blocks 0-7) + streaming cvt (blocks 8+) ----------------
__global__ __launch_bounds__(256) void perm_cvt(const int* __restrict__ sid,
                                                int* __restrict__ counts,
                                                int* __restrict__ offsets,
                                                int* __restrict__ perm,
                                                const float* __restrict__ x,
                                                unsigned short* __restrict__ xb){
  int b = blockIdx.x;
  int t = threadIdx.x;

  if (b >= 8){
    // streaming cast: 8192 floats per block, fully coalesced
    size_t base = (size_t)(b - 8) * 8192 + (size_t)t * 8;
    #pragma unroll
    for (int c = 0; c < 4; c++){
      size_t f = base + (size_t)c * 2048;
      f32x4 v0 = *(const f32x4*)(x + f);
      f32x4 v1 = *(const f32x4*)(x + f + 4);
      short8v o;
      o[0] = (short)f2bf(v0[0]); o[1] = (short)f2bf(v0[1]);
      o[2] = (short)f2bf(v0[2]); o[3] = (short)f2bf(v0[3]);
      o[4] = (short)f2bf(v1[0]); o[5] = (short)f2bf(v1[1]);
      o[6] = (short)f2bf(v1[2]); o[7] = (short)f2bf(v1[3]);
      *(short8v*)(xb + f) = o;
    }
    return;
  }

  // build_perm for subject s = b (stable compaction)
  int s = b;
  __shared__ int shs[NROWS];          // 32KB cached sid
  __shared__ int red_lt[4], red_eq[4], wsum[4];
  __shared__ int sh_base;

  int lane = t & 63, wv = t >> 6;
  int c_lt = 0, c_eq = 0;
  const int4v* sv = (const int4v*)sid;
  #pragma unroll
  for (int i = 0; i < NROWS / 4 / 256; i++){
    int idx = i * 256 + t;
    int4v v = sv[idx];
    *(int4v*)&shs[idx * 4] = v;
    #pragma unroll
    for (int e = 0; e < 4; e++){ c_lt += (v[e] < s); c_eq += (v[e] == s); }
  }
  #pragma unroll
  for (int d = 32; d >= 1; d >>= 1){
    c_lt += __shfl_xor(c_lt, d);
    c_eq += __shfl_xor(c_eq, d);
  }
  if (lane == 0){ red_lt[wv] = c_lt; red_eq[wv] = c_eq; }
  __syncthreads();
  if (t == 0){
    int lt = red_lt[0] + red_lt[1] + red_lt[2] + red_lt[3];
    int eq = red_eq[0] + red_eq[1] + red_eq[2] + red_eq[3];
    offsets[s] = lt;
    counts[s]  = eq;
    sh_base = lt;
  }
  __syncthreads();
  int base = sh_base;

  for (int c0 = 0; c0 < NROWS; c0 += 256){
    int v = shs[c0 + t];
    bool eq = (v == s);
    unsigned long long m = __ballot(eq);
    int rk = __popcll(m & ((1ull << lane) - 1ull));
    int wc = __popcll(m);
    if (lane == 0) wsum[wv] = wc;
    __syncthreads();
    int woff = 0;
    #pragma unroll
    for (int w = 0; w < 4; w++) if (w < wv) woff += wsum[w];
    int tot = wsum[0] + wsum[1] + wsum[2] + wsum[3];
    if (eq) perm[base + woff + rk] = c0 + t;
    base += tot;
    __syncthreads();
  }
}

// ---------------- K2: transpose + cvt W[s][k][o] -> Wt[s][o][k] bf16 ----------------
__global__ __launch_bounds__(256) void transpose_w(const float* __restrict__ W,
                                                   unsigned short* __restrict__ Wt){
  __shared__ float tile[64][65];
  int b = blockIdx.x;
  int t = threadIdx.x;
  int s  = b >> 9;                    // 0..7
  int kt = (b >> 4) & 31;             // 0..31
  int ot = b & 15;                    // 0..15
  int k0 = kt * 64, o0 = ot * 64;

  int kr  = t >> 4;
  int ol4 = (t & 15) * 4;
  bool lval = (o0 + ol4) < ODIM;

  const float* src = W + ((size_t)s * KDIM + k0) * ODIM + o0;
  #pragma unroll
  for (int it = 0; it < 4; it++){
    int k = kr + it * 16;
    f32x4 v = lval ? *(const f32x4*)(src + (size_t)k * ODIM + ol4)
                   : f32x4{0.f, 0.f, 0.f, 0.f};
    tile[k][ol4 + 0] = v[0]; tile[k][ol4 + 1] = v[1];
    tile[k][ol4 + 2] = v[2]; tile[k][ol4 + 3] = v[3];
  }
  __syncthreads();

  int j8   = (t & 7) * 8;
  int orow = t >> 3;
  unsigned short* dst = Wt + ((size_t)(s * OPAD + o0)) * KDIM + k0;
  #pragma unroll
  for (int it = 0; it < 2; it++){
    int o = orow + it * 32;
    bool oval = (o0 + o) < ODIM;
    short8v w;
    #pragma unroll
    for (int j = 0; j < 8; j++)
      w[j] = oval ? (short)f2bf(tile[j8 + j][o]) : (short)0;
    *(short8v*)(dst + (size_t)o * KDIM + j8) = w;
  }
}

// ---------------- K3: grouped bf16 MFMA GEMM, 160x256, 8 waves, 3-slot ring ----------------
// R13 schedule with ONE barrier per K-tile (was 4): within a tile both
// phases read the same slot (no hazard); stage targets slot+2 whose last
// readers finished before the previous tile-end barrier; counted VMN(7/6)
// before the tile-end barrier preserves the verified stage ledger. Waves
// skew within a tile -> one wave's MFMA overlaps another's ds_reads.
__global__ __launch_bounds__(512, 1) void gemm_bf16(
    const unsigned short* __restrict__ xb,   // [8192][2048] bf16 (orig order)
    const unsigned short* __restrict__ Wt,   // [8][1024][2048] bf16
    const int* __restrict__ counts,
    const int* __restrict__ offsets,
    const int* __restrict__ perm,
    const float* __restrict__ bias,          // [8][1000]
    float* __restrict__ out)                 // [8192][1000]
{
  int b  = blockIdx.x;
  int s  = b & 7;                 // subject == XCD
  int r  = b >> 3;
  int nt = r & 3;                 // 0..3
  int mt = r >> 2;                // 0..7
  int cnt = counts[s];
  int loc0 = mt * BM;
  if (loc0 >= cnt) return;
  int row0 = offsets[s] + loc0;
  int cnt_loc = cnt - loc0;

  __shared__ unsigned short L[3 * SLOT];     // 3 x 53248B ring
  __shared__ int permL[BM];

  int t = threadIdx.x;
  int lane = t & 63;
  int wave = t >> 6;              // 0..7

  int wm = (wave >> 2) * 80;      // 2M x 4N waves; wave-tile 80x64
  int wn = (wave & 3) << 6;
  int frow = lane & 15, fk = lane >> 4;
  int axor = frow & 7;

  int srck = (((lane & 7) ^ ((lane >> 3) & 7)) << 3);

  // prologue perm fetches: per-lane gathered A-rows + permL for epilogue
  int prow[5];
  if (wave < 4){
    #pragma unroll
    for (int i = 0; i < 5; i++){
      int row = ((wave * 5 + i) << 3) + (lane >> 3);      // 0..159
      int pidx = row0 + row; if (pidx > NROWS - 1) pidx = NROWS - 1;
      prow[i] = perm[pidx];
    }
  }
  {
    int pr = t;
    if (pr >= 320) pr -= 320;
    if (pr >= 160) pr -= 160;               // pr in [0,160)
    int pidx = row0 + pr; if (pidx > NROWS - 1) pidx = NROWS - 1;
    int pl = perm[pidx];
    asm volatile("s_waitcnt vmcnt(0)" ::: "memory");      // drain prologue
    __builtin_amdgcn_sched_barrier(0);
    permL[pr] = pl;
  }

  size_t gA[5]; unsigned loA[5];
  size_t gB[6]; unsigned loB[6];
  if (wave < 4){
    #pragma unroll
    for (int i = 0; i < 5; i++){
      int ca = wave * 5 + i;                 // 0..19
      gA[i]  = (size_t)prow[i] * KDIM + srck;
      loA[i] = (unsigned)((ca << 9) + (lane << 3));
    }
    #pragma unroll
    for (int j = 0; j < 2; j++){
      int cb  = wave * 2 + j;                // 0..7
      int row = (cb << 3) + (lane >> 3);
      gB[j]  = ((size_t)(s * OPAD + nt * BN + row)) * KDIM + srck;
      loB[j] = (unsigned)(ASLOT + (cb << 9) + (lane << 3));
    }
  } else {
    #pragma unroll
    for (int j = 0; j < 6; j++){
      int cb  = 8 + (wave - 4) * 6 + j;      // 8..31
      int row = (cb << 3) + (lane >> 3);
      gB[j]  = ((size_t)(s * OPAD + nt * BN + row)) * KDIM + srck;
      loB[j] = (unsigned)(ASLOT + (cb << 9) + (lane << 3));
    }
  }

  f32x4 acc[5][4];
  #pragma unroll
  for (int i = 0; i < 5; i++)
    #pragma unroll
    for (int j = 0; j < 4; j++)
      #pragma unroll
      for (int e = 0; e < 4; e++) acc[i][j][e] = 0.f;

#define STAGE_FULL(sl, koff) do { \
    unsigned short* Ls = &L[(sl) * SLOT]; \
    if (wave < 4){ \
      gload16(xb + gA[0] + (koff), (void*)(Ls + loA[0])); \
      gload16(xb + gA[1] + (koff), (void*)(Ls + loA[1])); \
      gload16(xb + gA[2] + (koff), (void*)(Ls + loA[2])); \
      gload16(xb + gA[3] + (koff), (void*)(Ls + loA[3])); \
      gload16(xb + gA[4] + (koff), (void*)(Ls + loA[4])); \
      gload16(Wt + gB[0] + (koff), (void*)(Ls + loB[0])); \
      gload16(Wt + gB[1] + (koff), (void*)(Ls + loB[1])); \
    } else { \
      gload16(Wt + gB[0] + (koff), (void*)(Ls + loB[0])); \
      gload16(Wt + gB[1] + (koff), (void*)(Ls + loB[1])); \
      gload16(Wt + gB[2] + (koff), (void*)(Ls + loB[2])); \
      gload16(Wt + gB[3] + (koff), (void*)(Ls + loB[3])); \
      gload16(Wt + gB[4] + (koff), (void*)(Ls + loB[4])); \
      gload16(Wt + gB[5] + (koff), (void*)(Ls + loB[5])); \
    } \
  } while (0)

#define STAGE_P0(sl, koff) do { \
    unsigned short* Ls = &L[(sl) * SLOT]; \
    if (wave < 4){ \
      gload16(xb + gA[0] + (koff), (void*)(Ls + loA[0])); \
      gload16(xb + gA[1] + (koff), (void*)(Ls + loA[1])); \
      gload16(xb + gA[2] + (koff), (void*)(Ls + loA[2])); \
      gload16(xb + gA[3] + (koff), (void*)(Ls + loA[3])); \
      gload16(xb + gA[4] + (koff), (void*)(Ls + loA[4])); \
    } else { \
      gload16(Wt + gB[0] + (koff), (void*)(Ls + loB[0])); \
      gload16(Wt + gB[1] + (koff), (void*)(Ls + loB[1])); \
      gload16(Wt + gB[2] + (koff), (void*)(Ls + loB[2])); \
    } \
  } while (0)
#define STAGE_P1(sl, koff) do { \
    unsigned short* Ls = &L[(sl) * SLOT]; \
    if (wave < 4){ \
      gload16(Wt + gB[0] + (koff), (void*)(Ls + loB[0])); \
      gload16(Wt + gB[1] + (koff), (void*)(Ls + loB[1])); \
    } else { \
      gload16(Wt + gB[3] + (koff), (void*)(Ls + loB[3])); \
      gload16(Wt + gB[4] + (koff), (void*)(Ls + loB[4])); \
      gload16(Wt + gB[5] + (koff), (void*)(Ls + loB[5])); \
    } \
  } while (0)

#define VMN() do { \
    if (wave < 4) asm volatile("s_waitcnt vmcnt(7)" ::: "memory"); \
    else          asm volatile("s_waitcnt vmcnt(6)" ::: "memory"); \
    __builtin_amdgcn_sched_barrier(0); \
  } while (0)
#define VM0() do { \
    asm volatile("s_waitcnt vmcnt(0)" ::: "memory"); \
    __builtin_amdgcn_sched_barrier(0); \
  } while (0)

#define AOFF(mi, ks) (((wm + ((mi) << 4) + frow) << 6) + ((((ks) * 4 + fk) ^ axor) << 3))
#define BOFF(ni, ks) (ASLOT + ((wn + ((ni) << 4) + frow) << 6) + ((((ks) * 4 + fk) ^ axor) << 3))
#define MF(mi, ni, av, bv) acc[mi][ni] = __builtin_amdgcn_mfma_f32_16x16x32_bf16(av, bv, acc[mi][ni], 0, 0, 0)

// one phase, NO barriers: 9 ds_read + stage-part -> lgkm(0) -> setprio MFMA
#define PH(sl, ks, STG) do { \
    const unsigned short* Lb = &L[(sl) * SLOT]; \
    short8v a0 = *(const short8v*)&Lb[AOFF(0, ks)]; \
    short8v a1 = *(const short8v*)&Lb[AOFF(1, ks)]; \
    short8v a2 = *(const short8v*)&Lb[AOFF(2, ks)]; \
    short8v a3 = *(const short8v*)&Lb[AOFF(3, ks)]; \
    short8v a4 = *(const short8v*)&Lb[AOFF(4, ks)]; \
    short8v b0 = *(const short8v*)&Lb[BOFF(0, ks)]; \
    short8v b1 = *(const short8v*)&Lb[BOFF(1, ks)]; \
    short8v b2 = *(const short8v*)&Lb[BOFF(2, ks)]; \
    short8v b3 = *(const short8v*)&Lb[BOFF(3, ks)]; \
    STG; \
    asm volatile("s_waitcnt lgkmcnt(0)" ::: "memory"); \
    __builtin_amdgcn_sched_barrier(0); \
    __builtin_amdgcn_s_setprio(1); \
    MF(0, 0, a0, b0); MF(1, 0, a1, b0); MF(2, 0, a2, b0); MF(3, 0, a3, b0); MF(4, 0, a4, b0); \
    MF(0, 1, a0, b1); MF(1, 1, a1, b1); MF(2, 1, a2, b1); MF(3, 1, a3, b1); MF(4, 1, a4, b1); \
    MF(0, 2, a0, b2); MF(1, 2, a1, b2); MF(2, 2, a2, b2); MF(3, 2, a3, b2); MF(4, 2, a4, b2); \
    MF(0, 3, a0, b3); MF(1, 3, a1, b3); MF(2, 3, a2, b3); MF(3, 3, a3, b3); MF(4, 3, a4, b3); \
    __builtin_amdgcn_s_setprio(0); \
  } while (0)

// one K-tile: 2 phases + counted wait + ONE barrier
#define TILE(sl, S0, S1, ENDW) do { \
    PH(sl, 0, S0); \
    PH(sl, 1, S1); \
    ENDW; \
    __builtin_amdgcn_s_barrier(); \
  } while (0)

  STAGE_FULL(0, 0);
  STAGE_FULL(1, BK);
  VMN();                                     // drain stage 0, leave stage 1
  __builtin_amdgcn_s_barrier();

  // main loop: tiles 0..29 (10 iters x 3 slots); stage t+2 split across phases
  for (int i = 0; i < 10; ++i){
    int kb = i * 3 * BK;
    TILE(0, STAGE_P0(2, kb + 2 * BK), STAGE_P1(2, kb + 2 * BK), VMN());
    TILE(1, STAGE_P0(0, kb + 3 * BK), STAGE_P1(0, kb + 3 * BK), VMN());
    TILE(2, STAGE_P0(1, kb + 4 * BK), STAGE_P1(1, kb + 4 * BK), VMN());
  }
  // tail: tile 30 drains stage(31); tile 31 plain
  TILE(0, , , VM0());
  PH(1, 0, );
  PH(1, 1, );

  // epilogue: C/D layout col=lane&15, row=(lane>>4)*4+reg
  float bvn[4]; int ocol[4];
  #pragma unroll
  for (int ni = 0; ni < 4; ni++){
    int o = nt * BN + wn + (ni << 4) + frow;
    ocol[ni] = o;
    bvn[ni] = (o < ODIM) ? bias[s * ODIM + o] : 0.f;
  }
  #pragma unroll
  for (int mi = 0; mi < 5; mi++){
    int rbase = wm + (mi << 4) + (fk << 2);
    #pragma unroll
    for (int jj = 0; jj < 4; jj++){
      int rr = rbase + jj;
      if (rr < cnt_loc){
        int orow = permL[rr];
        #pragma unroll
        for (int ni = 0; ni < 4; ni++){
          if (ocol[ni] < ODIM)
            out[(size_t)orow * ODIM + ocol[ni]] = acc[mi][ni][jj] + bvn[ni];
        }
      }
    }
  }
#undef STAGE_FULL
#undef STAGE_P0
#undef STAGE_P1
#undef VMN
#undef VM0
#undef AOFF
#undef BOFF
#undef MF
#undef PH
#undef TILE
}

// ---------------- fallback: naive fp32 (only if ws too small) ----------------
__global__ __launch_bounds__(256) void naive_kernel(const float* __restrict__ x,
                                                    const int* __restrict__ sid,
                                                    const float* __restrict__ W,
                                                    const float* __restrict__ bias,
                                                    float* __restrict__ out){
  __shared__ float xr[KDIM];
  int row = blockIdx.x;
  int s = sid[row];
  for (int i = threadIdx.x; i < KDIM; i += 256) xr[i] = x[(size_t)row * KDIM + i];
  __syncthreads();
  int o = blockIdx.y * 256 + threadIdx.x;
  if (o >= ODIM) return;
  const float* w = W + (size_t)s * KDIM * ODIM + o;
  float acc = bias[s * ODIM + o];
  for (int k = 0; k < KDIM; k++) acc = fmaf(xr[k], w[(size_t)k * ODIM], acc);
  out[(size_t)row * ODIM + o] = acc;
}

extern "C" void kernel_launch(void* const* d_in, const int* in_sizes, int n_in,
                              void* d_out, int out_size, void* d_ws, size_t ws_size,
                              hipStream_t stream) {
  const float* x    = (const float*)d_in[0];
  const int*   sid  = (const int*)d_in[1];
  const float* W    = (const float*)d_in[2];
  const float* bias = (const float*)d_in[3];
  float* out = (float*)d_out;

  const size_t XB_BYTES = (size_t)NROWS * KDIM * 2;
  const size_t WT_BYTES = (size_t)NSUB * OPAD * KDIM * 2;
  const size_t need = 64 + (size_t)NROWS * 4 + XB_BYTES + WT_BYTES;

  if (ws_size < need){
    naive_kernel<<<dim3(NROWS, 4), 256, 0, stream>>>(x, sid, W, bias, out);
    return;
  }

  char* w = (char*)d_ws;
  int* counts  = (int*)w;                      // 8 ints
  int* offsets = counts + 8;                   // 8 ints
  int* perm    = (int*)(w + 64);               // 8192 ints
  unsigned short* xb = (unsigned short*)(w + 64 + (size_t)NROWS * 4);
  unsigned short* Wt = xb + (size_t)NROWS * KDIM;

  perm_cvt    <<<8 + 2048, 256, 0, stream>>>(sid, counts, offsets, perm, x, xb);
  transpose_w <<<4096, 256, 0, stream>>>(W, Wt);
  gemm_bf16   <<<NSUB * 4 * MT_MAX, 512, 0, stream>>>(xb, Wt, counts, offsets, perm, bias, out);
}